// Round 5
// baseline (540.322 us; speedup 1.0000x reference)
//
#include <hip/hip_runtime.h>
#include <hip/hip_bf16.h>
#include <math.h>

#define B_ 2
#define S_ 2048
#define E_ 1024
#define H_ 16
#define D_ 64
#define TOK (B_*S_)          // 4096 tokens
#define SCALE 45.254833995939045f   // sqrt(2048): reference's softmax(scores / S**-0.5)

typedef __bf16 bf16x8 __attribute__((ext_vector_type(8)));
typedef float floatx4 __attribute__((ext_vector_type(4)));
struct b4s { __hip_bfloat16 x, y, z, w; };   // 8-byte packed bf16 quad

typedef const __attribute__((address_space(1))) char ga_char;
typedef __attribute__((address_space(3))) char ls_char;

// async 16B/lane global->LDS copy; lds dest = wave-uniform base + lane*16
__device__ __forceinline__ void gload_lds16(const void* g, ls_char* l) {
  __builtin_amdgcn_global_load_lds((ga_char*)g, l, 16, 0, 0);
}

// ---------------------------------------------------------------------------
// fp32 -> bf16 cast (for big weights)
// ---------------------------------------------------------------------------
__global__ __launch_bounds__(256) void cast_f2b(
    const float* __restrict__ in, __hip_bfloat16* __restrict__ out, int n4) {
  int i = blockIdx.x * 256 + threadIdx.x;
  if (i < n4) {
    float4 v = ((const float4*)in)[i];
    b4s o;
    o.x = __float2bfloat16(v.x); o.y = __float2bfloat16(v.y);
    o.z = __float2bfloat16(v.z); o.w = __float2bfloat16(v.w);
    *(b4s*)(out + (size_t)i * 4) = o;
  }
}

// ---------------------------------------------------------------------------
// Wq/Wk/Wv (64x64 fp32) -> hi/lo bf16 split, layout [m][2][4096]
// ---------------------------------------------------------------------------
__global__ __launch_bounds__(256) void cast_whl(
    const float* __restrict__ Wq, const float* __restrict__ Wk,
    const float* __restrict__ Wv, __hip_bfloat16* __restrict__ Whl) {
  const int idx = blockIdx.x * 256 + threadIdx.x;   // 0..3071
  const int m = idx >> 10;
  const int off = (idx & 1023) * 4;
  const float* W = (m == 0) ? Wq : (m == 1) ? Wk : Wv;
  float4 v = *(const float4*)(W + off);
  b4s hi, lo;
  hi.x = __float2bfloat16(v.x); lo.x = __float2bfloat16(v.x - __bfloat162float(hi.x));
  hi.y = __float2bfloat16(v.y); lo.y = __float2bfloat16(v.y - __bfloat162float(hi.y));
  hi.z = __float2bfloat16(v.z); lo.z = __float2bfloat16(v.z - __bfloat162float(hi.z));
  hi.w = __float2bfloat16(v.w); lo.w = __float2bfloat16(v.w - __bfloat162float(hi.w));
  *(b4s*)(Whl + (size_t)m * 8192 + off) = hi;
  *(b4s*)(Whl + (size_t)m * 8192 + 4096 + off) = lo;
}

// ---------------------------------------------------------------------------
// Fused QKV projection + hi/lo split + V transpose (unchanged from round 4)
// ---------------------------------------------------------------------------
__global__ __launch_bounds__(256) void qkv_fused(
    const float* __restrict__ xq, const float* __restrict__ xk,
    const float* __restrict__ xv, const __hip_bfloat16* __restrict__ Whl,
    __hip_bfloat16* __restrict__ qhi, __hip_bfloat16* __restrict__ qlo,
    __hip_bfloat16* __restrict__ khi, __hip_bfloat16* __restrict__ klo,
    __hip_bfloat16* __restrict__ vt) {
  __shared__ __bf16 Xh[2][64][32], Xl[2][64][32];
  __shared__ __bf16 Vt[64][72];
  const int t = threadIdx.x, lane = t & 63, w = t >> 6;
  const int quad = lane >> 4, low = lane & 15;
  const int bh = blockIdx.y;
  const int b = bh >> 4, h = bh & 15;
  const int s0 = blockIdx.x * 64;
  const int sr = t >> 2;
  const int sc = (t & 3) * 16;
  const int scc = sc >> 5, sco = sc & 31;

  for (int m = 0; m < 3; m++) {
    const float* xin = (m == 0) ? xq : (m == 1) ? xk : xv;
    const __hip_bfloat16* Wh = Whl + (size_t)m * 8192;

    __syncthreads();
    {
      const float* src = xin + ((size_t)(b * S_ + s0 + sr)) * E_ + h * 64 + sc;
      float4 f0 = *(const float4*)(src);
      float4 f1 = *(const float4*)(src + 4);
      float4 f2 = *(const float4*)(src + 8);
      float4 f3 = *(const float4*)(src + 12);
      float fv[16] = {f0.x, f0.y, f0.z, f0.w, f1.x, f1.y, f1.z, f1.w,
                      f2.x, f2.y, f2.z, f2.w, f3.x, f3.y, f3.z, f3.w};
      bf16x8 hi0, hi1, lo0, lo1;
      #pragma unroll
      for (int j = 0; j < 8; j++) {
        hi0[j] = (__bf16)fv[j];
        lo0[j] = (__bf16)(fv[j] - (float)hi0[j]);
        hi1[j] = (__bf16)fv[8 + j];
        lo1[j] = (__bf16)(fv[8 + j] - (float)hi1[j]);
      }
      *(bf16x8*)&Xh[scc][sr][sco] = hi0;
      *(bf16x8*)&Xh[scc][sr][sco + 8] = hi1;
      *(bf16x8*)&Xl[scc][sr][sco] = lo0;
      *(bf16x8*)&Xl[scc][sr][sco + 8] = lo1;
    }
    __syncthreads();

    bf16x8 ah[2], al[2];
    #pragma unroll
    for (int c = 0; c < 2; c++) {
      ah[c] = *(const bf16x8*)&Xh[c][w * 16 + low][quad * 8];
      al[c] = *(const bf16x8*)&Xl[c][w * 16 + low][quad * 8];
    }

    floatx4 acc[4];
    #pragma unroll
    for (int nn = 0; nn < 4; nn++) {
      floatx4 a = {};
      #pragma unroll
      for (int c = 0; c < 2; c++) {
        const __hip_bfloat16* wp = Wh + (nn * 16 + low) * 64 + c * 32 + quad * 8;
        bf16x8 wh_ = *(const bf16x8*)wp;
        bf16x8 wl_ = *(const bf16x8*)(wp + 4096);
        a = __builtin_amdgcn_mfma_f32_16x16x32_bf16(ah[c], wh_, a, 0, 0, 0);
        a = __builtin_amdgcn_mfma_f32_16x16x32_bf16(al[c], wh_, a, 0, 0, 0);
        a = __builtin_amdgcn_mfma_f32_16x16x32_bf16(ah[c], wl_, a, 0, 0, 0);
      }
      acc[nn] = a;
    }

    if (m < 2) {
      __hip_bfloat16* dh = (m == 0) ? qhi : khi;
      __hip_bfloat16* dl = (m == 0) ? qlo : klo;
      #pragma unroll
      for (int nn = 0; nn < 4; nn++) {
        #pragma unroll
        for (int i = 0; i < 4; i++) {
          const int s = s0 + w * 16 + quad * 4 + i;
          const int d = nn * 16 + low;
          const size_t adr = ((size_t)bh * S_ + s) * 64 + d;
          const float f = acc[nn][i];
          const __hip_bfloat16 hb = __float2bfloat16(f);
          dh[adr] = hb;
          dl[adr] = __float2bfloat16(f - __bfloat162float(hb));
        }
      }
    } else {
      #pragma unroll
      for (int nn = 0; nn < 4; nn++)
        #pragma unroll
        for (int i = 0; i < 4; i++)
          Vt[nn * 16 + low][w * 16 + quad * 4 + i] = (__bf16)acc[nn][i];
      __syncthreads();
      const int dr = t >> 2;
      const int scl = (t & 3) * 16;
      __hip_bfloat16* dst = vt + ((size_t)bh * 64 + dr) * S_ + s0 + scl;
      bf16x8 o0 = *(const bf16x8*)&Vt[dr][scl];
      bf16x8 o1 = *(const bf16x8*)&Vt[dr][scl + 8];
      *(bf16x8*)dst = o0;
      *(bf16x8*)(dst + 8) = o1;
    }
  }
}

// ---------------------------------------------------------------------------
// MFMA flash attention. Round-5 change: Ps rows padded 32->40 elems (80 B)
// so the 4 quads' rows no longer alias the same 16 banks on the scalar
// C->A-layout writes (4-way -> <=2-way, free per m136).
// ---------------------------------------------------------------------------
__global__ __launch_bounds__(256) void attn_mfma(
    const __hip_bfloat16* __restrict__ Qhi, const __hip_bfloat16* __restrict__ Qlo,
    const __hip_bfloat16* __restrict__ Khi, const __hip_bfloat16* __restrict__ Klo,
    const __hip_bfloat16* __restrict__ Vtg, __hip_bfloat16* __restrict__ ctx) {
  __shared__ __bf16 Qh[2][64][32], Ql[2][64][32];
  __shared__ __bf16 Kh[2][64][32], Kl[2][64][32];
  __shared__ __bf16 Vs[2][64][32];
  __shared__ __bf16 Ps[4][2][16][40];
  const int t = threadIdx.x, lane = t & 63, w = t >> 6;
  const int quad = lane >> 4, low = lane & 15;
  const int bh = blockIdx.y;
  const int q0 = blockIdx.x * 64;

  const int sr = t >> 2;
  const int sc = (t & 3) * 16;
  const int scc = sc >> 5, sco = sc & 31;

  {
    const size_t g = ((size_t)bh * S_ + q0 + sr) * 64 + sc;
    bf16x8 h0 = *(const bf16x8*)(Qhi + g);
    bf16x8 h1 = *(const bf16x8*)(Qhi + g + 8);
    bf16x8 l0 = *(const bf16x8*)(Qlo + g);
    bf16x8 l1 = *(const bf16x8*)(Qlo + g + 8);
    *(bf16x8*)&Qh[scc][sr][sco] = h0; *(bf16x8*)&Qh[scc][sr][sco + 8] = h1;
    *(bf16x8*)&Ql[scc][sr][sco] = l0; *(bf16x8*)&Ql[scc][sr][sco + 8] = l1;
  }
  __syncthreads();
  bf16x8 qh[2], ql[2];
  #pragma unroll
  for (int c = 0; c < 2; c++) {
    qh[c] = *(const bf16x8*)&Qh[c][w * 16 + low][quad * 8];
    ql[c] = *(const bf16x8*)&Ql[c][w * 16 + low][quad * 8];
  }

  floatx4 oacc[4] = {};
  float mrow[4], lrow[4];
  #pragma unroll
  for (int i = 0; i < 4; i++) { mrow[i] = -1e30f; lrow[i] = 0.f; }

  for (int kt = 0; kt < S_ / 64; kt++) {
    const size_t gk = ((size_t)bh * S_ + kt * 64 + sr) * 64 + sc;
    const size_t gv = ((size_t)bh * 64 + sr) * S_ + kt * 64 + sc;
    bf16x8 kh0 = *(const bf16x8*)(Khi + gk);
    bf16x8 kh1 = *(const bf16x8*)(Khi + gk + 8);
    bf16x8 kl0 = *(const bf16x8*)(Klo + gk);
    bf16x8 kl1 = *(const bf16x8*)(Klo + gk + 8);
    bf16x8 vv0 = *(const bf16x8*)(Vtg + gv);
    bf16x8 vv1 = *(const bf16x8*)(Vtg + gv + 8);
    __syncthreads();
    *(bf16x8*)&Kh[scc][sr][sco] = kh0; *(bf16x8*)&Kh[scc][sr][sco + 8] = kh1;
    *(bf16x8*)&Kl[scc][sr][sco] = kl0; *(bf16x8*)&Kl[scc][sr][sco + 8] = kl1;
    *(bf16x8*)&Vs[scc][sr][sco] = vv0; *(bf16x8*)&Vs[scc][sr][sco + 8] = vv1;
    __syncthreads();

    floatx4 sa[4];
    #pragma unroll
    for (int nn = 0; nn < 4; nn++) {
      bf16x8 kh[2], kl[2];
      #pragma unroll
      for (int c = 0; c < 2; c++) {
        kh[c] = *(const bf16x8*)&Kh[c][nn * 16 + low][quad * 8];
        kl[c] = *(const bf16x8*)&Kl[c][nn * 16 + low][quad * 8];
      }
      floatx4 s = {};
      s = __builtin_amdgcn_mfma_f32_16x16x32_bf16(qh[0], kh[0], s, 0, 0, 0);
      s = __builtin_amdgcn_mfma_f32_16x16x32_bf16(qh[1], kh[1], s, 0, 0, 0);
      s = __builtin_amdgcn_mfma_f32_16x16x32_bf16(ql[0], kh[0], s, 0, 0, 0);
      s = __builtin_amdgcn_mfma_f32_16x16x32_bf16(ql[1], kh[1], s, 0, 0, 0);
      s = __builtin_amdgcn_mfma_f32_16x16x32_bf16(qh[0], kl[0], s, 0, 0, 0);
      s = __builtin_amdgcn_mfma_f32_16x16x32_bf16(qh[1], kl[1], s, 0, 0, 0);
      sa[nn] = s;
    }

    float pv[4][4];
    #pragma unroll
    for (int i = 0; i < 4; i++) {
      float s0 = sa[0][i] * SCALE, s1 = sa[1][i] * SCALE;
      float s2 = sa[2][i] * SCALE, s3 = sa[3][i] * SCALE;
      float rmax = fmaxf(fmaxf(s0, s1), fmaxf(s2, s3));
      rmax = fmaxf(rmax, __shfl_xor(rmax, 1, 64));
      rmax = fmaxf(rmax, __shfl_xor(rmax, 2, 64));
      rmax = fmaxf(rmax, __shfl_xor(rmax, 4, 64));
      rmax = fmaxf(rmax, __shfl_xor(rmax, 8, 64));
      const float nm = fmaxf(mrow[i], rmax);
      const float al = __expf(mrow[i] - nm);
      mrow[i] = nm;
      const float p0 = __expf(s0 - nm), p1 = __expf(s1 - nm);
      const float p2 = __expf(s2 - nm), p3 = __expf(s3 - nm);
      pv[0][i] = p0; pv[1][i] = p1; pv[2][i] = p2; pv[3][i] = p3;
      float rs = (p0 + p1) + (p2 + p3);
      rs += __shfl_xor(rs, 1, 64);
      rs += __shfl_xor(rs, 2, 64);
      rs += __shfl_xor(rs, 4, 64);
      rs += __shfl_xor(rs, 8, 64);
      lrow[i] = lrow[i] * al + rs;
      oacc[0][i] *= al; oacc[1][i] *= al; oacc[2][i] *= al; oacc[3][i] *= al;
    }

    #pragma unroll
    for (int nn = 0; nn < 4; nn++)
      #pragma unroll
      for (int i = 0; i < 4; i++)
        Ps[w][nn >> 1][quad * 4 + i][(nn & 1) * 16 + low] = (__bf16)pv[nn][i];
    bf16x8 pa0 = *(const bf16x8*)&Ps[w][0][low][quad * 8];
    bf16x8 pa1 = *(const bf16x8*)&Ps[w][1][low][quad * 8];

    #pragma unroll
    for (int dt = 0; dt < 4; dt++) {
      bf16x8 vb0 = *(const bf16x8*)&Vs[0][dt * 16 + low][quad * 8];
      bf16x8 vb1 = *(const bf16x8*)&Vs[1][dt * 16 + low][quad * 8];
      oacc[dt] = __builtin_amdgcn_mfma_f32_16x16x32_bf16(pa0, vb0, oacc[dt], 0, 0, 0);
      oacc[dt] = __builtin_amdgcn_mfma_f32_16x16x32_bf16(pa1, vb1, oacc[dt], 0, 0, 0);
    }
  }

  const int b = bh >> 4, h = bh & 15;
  #pragma unroll
  for (int i = 0; i < 4; i++) {
    const float inv = 1.0f / lrow[i];
    const int row = q0 + w * 16 + quad * 4 + i;
    const size_t base = ((size_t)(b * S_ + row)) * E_ + h * 64 + low;
    #pragma unroll
    for (int dt = 0; dt < 4; dt++)
      ctx[base + dt * 16] = __float2bfloat16(oacc[dt][i] * inv);
  }
}

// ---------------------------------------------------------------------------
// bf16 MFMA GEMM. Round-5: m97-style global_load_lds(16B) staging (staging
// map is lane-contiguous: thread t -> LDS flat byte t*16, so dest =
// wave base + lane*16), optional split-K via blockIdx.z with fp32 atomicAdd
// epilogue (Cout pre-zeroed by hipMemsetAsync; bias applied downstream).
// ---------------------------------------------------------------------------
template <int RELU, int OUT_BF16, int ATOMIC>
__global__ __launch_bounds__(256) void gemm_mfma(
    const __hip_bfloat16* __restrict__ A, const __hip_bfloat16* __restrict__ Wt,
    const float* __restrict__ bias, void* __restrict__ Cout,
    int M, int N, int Kblk, int lda) {
  __shared__ __bf16 As[128][32];
  __shared__ __bf16 Bs[128][32];
  const int t = threadIdx.x;
  const int lane = t & 63;
  const int w = t >> 6;
  const int wr = w >> 1, wc = w & 1;
  const int m0 = blockIdx.y * 128, n0 = blockIdx.x * 128;

  A += (size_t)blockIdx.z * Kblk;
  Wt += (size_t)blockIdx.z * Kblk;

  floatx4 acc[4][4] = {};
  const int srow = t >> 2;
  const int schunk = (t & 3) * 8;

  const __hip_bfloat16* gA0 = A + (size_t)(m0 + srow) * lda + schunk;
  const __hip_bfloat16* gA1 = A + (size_t)(m0 + srow + 64) * lda + schunk;
  const __hip_bfloat16* gB0 = Wt + (size_t)(n0 + srow) * lda + schunk;
  const __hip_bfloat16* gB1 = Wt + (size_t)(n0 + srow + 64) * lda + schunk;
  ls_char* lA = (ls_char*)&As[0][0] + w * 1024;
  ls_char* lB = (ls_char*)&Bs[0][0] + w * 1024;

  for (int k0 = 0; k0 < Kblk; k0 += 32) {
    __syncthreads();                 // all waves done reading previous tile
    gload_lds16(gA0 + k0, lA);
    gload_lds16(gA1 + k0, lA + 4096);
    gload_lds16(gB0 + k0, lB);
    gload_lds16(gB1 + k0, lB + 4096);
    __syncthreads();                 // vmcnt(0) drain -> tile resident

    bf16x8 af[4], bf[4];
    #pragma unroll
    for (int i = 0; i < 4; i++) {
      af[i] = *(const bf16x8*)&As[wr * 64 + i * 16 + (lane & 15)][(lane >> 4) * 8];
      bf[i] = *(const bf16x8*)&Bs[wc * 64 + i * 16 + (lane & 15)][(lane >> 4) * 8];
    }
    #pragma unroll
    for (int mi = 0; mi < 4; mi++)
      #pragma unroll
      for (int ni = 0; ni < 4; ni++)
        acc[mi][ni] = __builtin_amdgcn_mfma_f32_16x16x32_bf16(
            af[mi], bf[ni], acc[mi][ni], 0, 0, 0);
  }

  const int cil = lane & 15;
  const int quad = lane >> 4;
  #pragma unroll
  for (int ni = 0; ni < 4; ni++) {
    const int col = n0 + wc * 64 + ni * 16 + cil;
    const float bb = ATOMIC ? 0.f : bias[col];
    #pragma unroll
    for (int mi = 0; mi < 4; mi++) {
      const int row = m0 + wr * 64 + mi * 16 + quad * 4;
      #pragma unroll
      for (int i = 0; i < 4; i++) {
        if (ATOMIC) {
          atomicAdd((float*)Cout + (size_t)(row + i) * N + col, acc[mi][ni][i]);
        } else {
          float vv = acc[mi][ni][i] + bb;
          if (RELU) vv = fmaxf(vv, 0.f);
          if (OUT_BF16)
            ((__hip_bfloat16*)Cout)[(size_t)(row + i) * N + col] = __float2bfloat16(vv);
          else
            ((float*)Cout)[(size_t)(row + i) * N + col] = vv;
        }
      }
    }
  }
}

// ---------------------------------------------------------------------------
// out = LayerNorm(a + bias + r)*g + b ; optional secondary bf16 output.
// bias folded here for the split-K GEMMs (added BEFORE the LN stats,
// matching reference att+queries -> LN ordering).
// ---------------------------------------------------------------------------
template <int EMIT_BF16>
__global__ __launch_bounds__(256) void add_ln(
    const float* __restrict__ a, const float* __restrict__ r,
    const float* __restrict__ bias,
    const float* __restrict__ g, const float* __restrict__ bt,
    float* __restrict__ out, __hip_bfloat16* __restrict__ outb) {
  __shared__ float red[16];
  const int tok = blockIdx.x, t = threadIdx.x;
  float4 av = ((const float4*)(a + (size_t)tok * E_))[t];
  float4 rv = ((const float4*)(r + (size_t)tok * E_))[t];
  float4 cv = ((const float4*)bias)[t];
  float4 x;
  x.x = av.x + rv.x + cv.x; x.y = av.y + rv.y + cv.y;
  x.z = av.z + rv.z + cv.z; x.w = av.w + rv.w + cv.w;
  float sum = x.x + x.y + x.z + x.w;
  float ssq = x.x * x.x + x.y * x.y + x.z * x.z + x.w * x.w;
  #pragma unroll
  for (int off = 32; off >= 1; off >>= 1) {
    sum += __shfl_down(sum, off, 64);
    ssq += __shfl_down(ssq, off, 64);
  }
  const int wave = t >> 6;
  if ((t & 63) == 0) { red[wave] = sum; red[4 + wave] = ssq; }
  __syncthreads();
  if (t == 0) {
    float s = red[0] + red[1] + red[2] + red[3];
    float qq = red[4] + red[5] + red[6] + red[7];
    float mu = s * (1.0f / E_);
    red[8] = mu;
    red[9] = qq * (1.0f / E_) - mu * mu;
  }
  __syncthreads();
  const float mu = red[8];
  const float inv = rsqrtf(red[9] + 1e-5f);
  float4 gv = ((const float4*)g)[t];
  float4 bv = ((const float4*)bt)[t];
  float4 o;
  o.x = (x.x - mu) * inv * gv.x + bv.x;
  o.y = (x.y - mu) * inv * gv.y + bv.y;
  o.z = (x.z - mu) * inv * gv.z + bv.z;
  o.w = (x.w - mu) * inv * gv.w + bv.w;
  ((float4*)(out + (size_t)tok * E_))[t] = o;
  if (EMIT_BF16) {
    b4s ob;
    ob.x = __float2bfloat16(o.x); ob.y = __float2bfloat16(o.y);
    ob.z = __float2bfloat16(o.z); ob.w = __float2bfloat16(o.w);
    *(b4s*)(outb + (size_t)tok * E_ + t * 4) = ob;
  }
}

// ---------------------------------------------------------------------------
extern "C" void kernel_launch(void* const* d_in, const int* in_sizes, int n_in,
                              void* d_out, int out_size, void* d_ws, size_t ws_size,
                              hipStream_t stream) {
  const float* queries = (const float*)d_in[0];
  const float* keys    = (const float*)d_in[1];
  const float* values  = (const float*)d_in[2];
  const float* Wq  = (const float*)d_in[4];
  const float* Wk  = (const float*)d_in[5];
  const float* Wv  = (const float*)d_in[6];
  const float* Wfc = (const float*)d_in[7];
  const float* bfc = (const float*)d_in[8];
  const float* W1  = (const float*)d_in[9];
  const float* b1  = (const float*)d_in[10];
  const float* W2  = (const float*)d_in[11];
  const float* b2  = (const float*)d_in[12];
  const float* ln1_g = (const float*)d_in[13];
  const float* ln1_b = (const float*)d_in[14];
  const float* ln2_g = (const float*)d_in[15];
  const float* ln2_b = (const float*)d_in[16];

  const size_t M1 = 1048576;
  float* ws = (float*)d_ws;
  float* ATT = ws;             // 4M fl (atomic accum, zeroed)
  float* Hf  = ws + 4 * M1;    // 4M fl
  float* X   = ws + 8 * M1;    // 4M fl (atomic accum, zeroed)
  __hip_bfloat16* bb = (__hip_bfloat16*)(ws + 12 * M1);
  __hip_bfloat16* CTXb = bb;                  //  4M
  __hip_bfloat16* Hb   = bb + 4 * M1;         //  4M
  __hip_bfloat16* Wfcb = bb + 8 * M1;         //  1M
  __hip_bfloat16* W1b  = bb + 9 * M1;         //  4M
  __hip_bfloat16* W2b  = bb + 13 * M1;        //  4M
  // attention temps (17M..37M) alias FF1b (17M..33M): FF1b written after attn
  __hip_bfloat16* Qhi  = bb + 17 * M1;        //  4M
  __hip_bfloat16* Qlo  = bb + 21 * M1;        //  4M
  __hip_bfloat16* Khi  = bb + 25 * M1;        //  4M
  __hip_bfloat16* Klo  = bb + 29 * M1;        //  4M
  __hip_bfloat16* Vtb  = bb + 33 * M1;        //  4M
  __hip_bfloat16* FF1b = bb + 17 * M1;        // 16M (after attention)
  __hip_bfloat16* Whlb = bb + 37 * M1;        // 24K
  float* out = (float*)d_out;

  // zero the split-K atomic accumulators (ws is re-poisoned every launch)
  hipMemsetAsync(ATT, 0, 4 * M1 * sizeof(float), stream);
  hipMemsetAsync(X, 0, 4 * M1 * sizeof(float), stream);

  cast_f2b<<<(E_ * E_ / 4 + 255) / 256, 256, 0, stream>>>(Wfc, Wfcb, E_ * E_ / 4);
  cast_f2b<<<(4 * E_ * E_ / 4 + 255) / 256, 256, 0, stream>>>(W1, W1b, 4 * E_ * E_ / 4);
  cast_f2b<<<(4 * E_ * E_ / 4 + 255) / 256, 256, 0, stream>>>(W2, W2b, 4 * E_ * E_ / 4);
  cast_whl<<<12, 256, 0, stream>>>(Wq, Wk, Wv, Whlb);

  qkv_fused<<<dim3(S_ / 64, B_ * H_), 256, 0, stream>>>(
      queries, keys, values, Whlb, Qhi, Qlo, Khi, Klo, Vtb);
  attn_mfma<<<dim3(S_ / 64, B_ * H_), 256, 0, stream>>>(Qhi, Qlo, Khi, Klo, Vtb, CTXb);
  // fc: split-K=2 (K=1024 -> 512/block), atomic fp32 into ATT; bias in add_ln
  gemm_mfma<0, 0, 1><<<dim3(E_ / 128, TOK / 128, 2), 256, 0, stream>>>(
      CTXb, Wfcb, nullptr, ATT, TOK, E_, 512, E_);
  add_ln<1><<<TOK, 256, 0, stream>>>(ATT, queries, bfc, ln1_g, ln1_b, Hf, Hb);
  // FFN1: full-K, bias+ReLU, bf16 out (grid 1024 -> plenty of blocks/CU)
  gemm_mfma<1, 1, 0><<<dim3(4 * E_ / 128, TOK / 128, 1), 256, 0, stream>>>(
      Hb, W1b, b1, FF1b, TOK, 4 * E_, E_, E_);
  // FFN2: split-K=2 (K=4096 -> 2048/block), atomic fp32 into X; bias in add_ln
  gemm_mfma<0, 0, 1><<<dim3(E_ / 128, TOK / 128, 2), 256, 0, stream>>>(
      FF1b, W2b, nullptr, X, TOK, E_, 2048, 4 * E_);
  add_ln<0><<<TOK, 256, 0, stream>>>(X, Hf, b2, ln2_g, ln2_b, out, nullptr);
}

// Round 6
// 502.789 us; speedup vs baseline: 1.0746x; 1.0746x over previous
//
#include <hip/hip_runtime.h>
#include <hip/hip_bf16.h>
#include <math.h>

#define B_ 2
#define S_ 2048
#define E_ 1024
#define H_ 16
#define D_ 64
#define TOK (B_*S_)          // 4096 tokens
#define SCALE 45.254833995939045f   // sqrt(2048): reference's softmax(scores / S**-0.5)

typedef __bf16 bf16x8 __attribute__((ext_vector_type(8)));
typedef float floatx4 __attribute__((ext_vector_type(4)));
struct b4s { __hip_bfloat16 x, y, z, w; };   // 8-byte packed bf16 quad

typedef const __attribute__((address_space(1))) char ga_char;
typedef __attribute__((address_space(3))) char ls_char;

// async 16B/lane global->LDS copy; lds dest = wave-uniform base + lane*16
__device__ __forceinline__ void gload_lds16(const void* g, ls_char* l) {
  __builtin_amdgcn_global_load_lds((ga_char*)g, l, 16, 0, 0);
}

// XOR bank swizzle for [2][64][32]-bf16 tiles: logical 16B chunk qpos (0..3)
// of row r lives at physical chunk qpos^(r&3). Removes the 4-way aliasing of
// b128 fragment reads (rows 2 apart share banks in the natural layout).
#define SWZ(arr, half, row, qpos) \
  (*(bf16x8*)&arr[half][row][(((qpos) ^ ((row) & 3)) * 8)])

// ---------------------------------------------------------------------------
// fp32 -> bf16 cast (for big weights)
// ---------------------------------------------------------------------------
__global__ __launch_bounds__(256) void cast_f2b(
    const float* __restrict__ in, __hip_bfloat16* __restrict__ out, int n4) {
  int i = blockIdx.x * 256 + threadIdx.x;
  if (i < n4) {
    float4 v = ((const float4*)in)[i];
    b4s o;
    o.x = __float2bfloat16(v.x); o.y = __float2bfloat16(v.y);
    o.z = __float2bfloat16(v.z); o.w = __float2bfloat16(v.w);
    *(b4s*)(out + (size_t)i * 4) = o;
  }
}

// ---------------------------------------------------------------------------
// Wq/Wk/Wv (64x64 fp32) -> hi/lo bf16 split, layout [m][2][4096]
// ---------------------------------------------------------------------------
__global__ __launch_bounds__(256) void cast_whl(
    const float* __restrict__ Wq, const float* __restrict__ Wk,
    const float* __restrict__ Wv, __hip_bfloat16* __restrict__ Whl) {
  const int idx = blockIdx.x * 256 + threadIdx.x;   // 0..3071
  const int m = idx >> 10;
  const int off = (idx & 1023) * 4;
  const float* W = (m == 0) ? Wq : (m == 1) ? Wk : Wv;
  float4 v = *(const float4*)(W + off);
  b4s hi, lo;
  hi.x = __float2bfloat16(v.x); lo.x = __float2bfloat16(v.x - __bfloat162float(hi.x));
  hi.y = __float2bfloat16(v.y); lo.y = __float2bfloat16(v.y - __bfloat162float(hi.y));
  hi.z = __float2bfloat16(v.z); lo.z = __float2bfloat16(v.z - __bfloat162float(hi.z));
  hi.w = __float2bfloat16(v.w); lo.w = __float2bfloat16(v.w - __bfloat162float(hi.w));
  *(b4s*)(Whl + (size_t)m * 8192 + off) = hi;
  *(b4s*)(Whl + (size_t)m * 8192 + 4096 + off) = lo;
}

// ---------------------------------------------------------------------------
// Fused QKV projection + hi/lo split + V transpose. Round-6: swizzled Xh/Xl.
// ---------------------------------------------------------------------------
__global__ __launch_bounds__(256) void qkv_fused(
    const float* __restrict__ xq, const float* __restrict__ xk,
    const float* __restrict__ xv, const __hip_bfloat16* __restrict__ Whl,
    __hip_bfloat16* __restrict__ qhi, __hip_bfloat16* __restrict__ qlo,
    __hip_bfloat16* __restrict__ khi, __hip_bfloat16* __restrict__ klo,
    __hip_bfloat16* __restrict__ vt) {
  __shared__ __bf16 Xh[2][64][32], Xl[2][64][32];
  __shared__ __bf16 Vt[64][72];
  const int t = threadIdx.x, lane = t & 63, w = t >> 6;
  const int quad = lane >> 4, low = lane & 15;
  const int bh = blockIdx.y;
  const int b = bh >> 4, h = bh & 15;
  const int s0 = blockIdx.x * 64;
  const int sr = t >> 2;
  const int sc = (t & 3) * 16;
  const int scc = sc >> 5;
  const int p0 = (sc & 31) >> 3;   // logical 16B chunk within half: 0 or 2

  for (int m = 0; m < 3; m++) {
    const float* xin = (m == 0) ? xq : (m == 1) ? xk : xv;
    const __hip_bfloat16* Wh = Whl + (size_t)m * 8192;

    __syncthreads();
    {
      const float* src = xin + ((size_t)(b * S_ + s0 + sr)) * E_ + h * 64 + sc;
      float4 f0 = *(const float4*)(src);
      float4 f1 = *(const float4*)(src + 4);
      float4 f2 = *(const float4*)(src + 8);
      float4 f3 = *(const float4*)(src + 12);
      float fv[16] = {f0.x, f0.y, f0.z, f0.w, f1.x, f1.y, f1.z, f1.w,
                      f2.x, f2.y, f2.z, f2.w, f3.x, f3.y, f3.z, f3.w};
      bf16x8 hi0, hi1, lo0, lo1;
      #pragma unroll
      for (int j = 0; j < 8; j++) {
        hi0[j] = (__bf16)fv[j];
        lo0[j] = (__bf16)(fv[j] - (float)hi0[j]);
        hi1[j] = (__bf16)fv[8 + j];
        lo1[j] = (__bf16)(fv[8 + j] - (float)hi1[j]);
      }
      SWZ(Xh, scc, sr, p0) = hi0;
      SWZ(Xh, scc, sr, p0 + 1) = hi1;
      SWZ(Xl, scc, sr, p0) = lo0;
      SWZ(Xl, scc, sr, p0 + 1) = lo1;
    }
    __syncthreads();

    bf16x8 ah[2], al[2];
    #pragma unroll
    for (int c = 0; c < 2; c++) {
      ah[c] = SWZ(Xh, c, w * 16 + low, quad);
      al[c] = SWZ(Xl, c, w * 16 + low, quad);
    }

    floatx4 acc[4];
    #pragma unroll
    for (int nn = 0; nn < 4; nn++) {
      floatx4 a = {};
      #pragma unroll
      for (int c = 0; c < 2; c++) {
        const __hip_bfloat16* wp = Wh + (nn * 16 + low) * 64 + c * 32 + quad * 8;
        bf16x8 wh_ = *(const bf16x8*)wp;
        bf16x8 wl_ = *(const bf16x8*)(wp + 4096);
        a = __builtin_amdgcn_mfma_f32_16x16x32_bf16(ah[c], wh_, a, 0, 0, 0);
        a = __builtin_amdgcn_mfma_f32_16x16x32_bf16(al[c], wh_, a, 0, 0, 0);
        a = __builtin_amdgcn_mfma_f32_16x16x32_bf16(ah[c], wl_, a, 0, 0, 0);
      }
      acc[nn] = a;
    }

    if (m < 2) {
      __hip_bfloat16* dh = (m == 0) ? qhi : khi;
      __hip_bfloat16* dl = (m == 0) ? qlo : klo;
      #pragma unroll
      for (int nn = 0; nn < 4; nn++) {
        #pragma unroll
        for (int i = 0; i < 4; i++) {
          const int s = s0 + w * 16 + quad * 4 + i;
          const int d = nn * 16 + low;
          const size_t adr = ((size_t)bh * S_ + s) * 64 + d;
          const float f = acc[nn][i];
          const __hip_bfloat16 hb = __float2bfloat16(f);
          dh[adr] = hb;
          dl[adr] = __float2bfloat16(f - __bfloat162float(hb));
        }
      }
    } else {
      #pragma unroll
      for (int nn = 0; nn < 4; nn++)
        #pragma unroll
        for (int i = 0; i < 4; i++)
          Vt[nn * 16 + low][w * 16 + quad * 4 + i] = (__bf16)acc[nn][i];
      __syncthreads();
      const int dr = t >> 2;
      const int scl = (t & 3) * 16;
      __hip_bfloat16* dst = vt + ((size_t)bh * 64 + dr) * S_ + s0 + scl;
      bf16x8 o0 = *(const bf16x8*)&Vt[dr][scl];
      bf16x8 o1 = *(const bf16x8*)&Vt[dr][scl + 8];
      *(bf16x8*)dst = o0;
      *(bf16x8*)(dst + 8) = o1;
    }
  }
}

// ---------------------------------------------------------------------------
// MFMA flash attention. Round-6: XOR-swizzled K/V/Q tile layouts (kills the
// 4-way b128 fragment-read bank conflicts). Ps keeps the 40-pad.
// ---------------------------------------------------------------------------
__global__ __launch_bounds__(256) void attn_mfma(
    const __hip_bfloat16* __restrict__ Qhi, const __hip_bfloat16* __restrict__ Qlo,
    const __hip_bfloat16* __restrict__ Khi, const __hip_bfloat16* __restrict__ Klo,
    const __hip_bfloat16* __restrict__ Vtg, __hip_bfloat16* __restrict__ ctx) {
  __shared__ __bf16 Qh[2][64][32], Ql[2][64][32];
  __shared__ __bf16 Kh[2][64][32], Kl[2][64][32];
  __shared__ __bf16 Vs[2][64][32];
  __shared__ __bf16 Ps[4][2][16][40];
  const int t = threadIdx.x, lane = t & 63, w = t >> 6;
  const int quad = lane >> 4, low = lane & 15;
  const int bh = blockIdx.y;
  const int q0 = blockIdx.x * 64;

  const int sr = t >> 2;
  const int sc = (t & 3) * 16;
  const int scc = sc >> 5;
  const int p0 = (sc & 31) >> 3;   // 0 or 2

  {
    const size_t g = ((size_t)bh * S_ + q0 + sr) * 64 + sc;
    bf16x8 h0 = *(const bf16x8*)(Qhi + g);
    bf16x8 h1 = *(const bf16x8*)(Qhi + g + 8);
    bf16x8 l0 = *(const bf16x8*)(Qlo + g);
    bf16x8 l1 = *(const bf16x8*)(Qlo + g + 8);
    SWZ(Qh, scc, sr, p0) = h0; SWZ(Qh, scc, sr, p0 + 1) = h1;
    SWZ(Ql, scc, sr, p0) = l0; SWZ(Ql, scc, sr, p0 + 1) = l1;
  }
  __syncthreads();
  bf16x8 qh[2], ql[2];
  #pragma unroll
  for (int c = 0; c < 2; c++) {
    qh[c] = SWZ(Qh, c, w * 16 + low, quad);
    ql[c] = SWZ(Ql, c, w * 16 + low, quad);
  }

  floatx4 oacc[4] = {};
  float mrow[4], lrow[4];
  #pragma unroll
  for (int i = 0; i < 4; i++) { mrow[i] = -1e30f; lrow[i] = 0.f; }

  for (int kt = 0; kt < S_ / 64; kt++) {
    const size_t gk = ((size_t)bh * S_ + kt * 64 + sr) * 64 + sc;
    const size_t gv = ((size_t)bh * 64 + sr) * S_ + kt * 64 + sc;
    bf16x8 kh0 = *(const bf16x8*)(Khi + gk);
    bf16x8 kh1 = *(const bf16x8*)(Khi + gk + 8);
    bf16x8 kl0 = *(const bf16x8*)(Klo + gk);
    bf16x8 kl1 = *(const bf16x8*)(Klo + gk + 8);
    bf16x8 vv0 = *(const bf16x8*)(Vtg + gv);
    bf16x8 vv1 = *(const bf16x8*)(Vtg + gv + 8);
    __syncthreads();
    SWZ(Kh, scc, sr, p0) = kh0; SWZ(Kh, scc, sr, p0 + 1) = kh1;
    SWZ(Kl, scc, sr, p0) = kl0; SWZ(Kl, scc, sr, p0 + 1) = kl1;
    SWZ(Vs, scc, sr, p0) = vv0; SWZ(Vs, scc, sr, p0 + 1) = vv1;
    __syncthreads();

    floatx4 sa[4];
    #pragma unroll
    for (int nn = 0; nn < 4; nn++) {
      bf16x8 kh[2], kl[2];
      #pragma unroll
      for (int c = 0; c < 2; c++) {
        kh[c] = SWZ(Kh, c, nn * 16 + low, quad);
        kl[c] = SWZ(Kl, c, nn * 16 + low, quad);
      }
      floatx4 s = {};
      s = __builtin_amdgcn_mfma_f32_16x16x32_bf16(qh[0], kh[0], s, 0, 0, 0);
      s = __builtin_amdgcn_mfma_f32_16x16x32_bf16(qh[1], kh[1], s, 0, 0, 0);
      s = __builtin_amdgcn_mfma_f32_16x16x32_bf16(ql[0], kh[0], s, 0, 0, 0);
      s = __builtin_amdgcn_mfma_f32_16x16x32_bf16(ql[1], kh[1], s, 0, 0, 0);
      s = __builtin_amdgcn_mfma_f32_16x16x32_bf16(qh[0], kl[0], s, 0, 0, 0);
      s = __builtin_amdgcn_mfma_f32_16x16x32_bf16(qh[1], kl[1], s, 0, 0, 0);
      sa[nn] = s;
    }

    float pv[4][4];
    #pragma unroll
    for (int i = 0; i < 4; i++) {
      float s0 = sa[0][i] * SCALE, s1 = sa[1][i] * SCALE;
      float s2 = sa[2][i] * SCALE, s3 = sa[3][i] * SCALE;
      float rmax = fmaxf(fmaxf(s0, s1), fmaxf(s2, s3));
      rmax = fmaxf(rmax, __shfl_xor(rmax, 1, 64));
      rmax = fmaxf(rmax, __shfl_xor(rmax, 2, 64));
      rmax = fmaxf(rmax, __shfl_xor(rmax, 4, 64));
      rmax = fmaxf(rmax, __shfl_xor(rmax, 8, 64));
      const float nm = fmaxf(mrow[i], rmax);
      const float al = __expf(mrow[i] - nm);
      mrow[i] = nm;
      const float p0_ = __expf(s0 - nm), p1_ = __expf(s1 - nm);
      const float p2_ = __expf(s2 - nm), p3_ = __expf(s3 - nm);
      pv[0][i] = p0_; pv[1][i] = p1_; pv[2][i] = p2_; pv[3][i] = p3_;
      float rs = (p0_ + p1_) + (p2_ + p3_);
      rs += __shfl_xor(rs, 1, 64);
      rs += __shfl_xor(rs, 2, 64);
      rs += __shfl_xor(rs, 4, 64);
      rs += __shfl_xor(rs, 8, 64);
      lrow[i] = lrow[i] * al + rs;
      oacc[0][i] *= al; oacc[1][i] *= al; oacc[2][i] *= al; oacc[3][i] *= al;
    }

    #pragma unroll
    for (int nn = 0; nn < 4; nn++)
      #pragma unroll
      for (int i = 0; i < 4; i++)
        Ps[w][nn >> 1][quad * 4 + i][(nn & 1) * 16 + low] = (__bf16)pv[nn][i];
    bf16x8 pa0 = *(const bf16x8*)&Ps[w][0][low][quad * 8];
    bf16x8 pa1 = *(const bf16x8*)&Ps[w][1][low][quad * 8];

    #pragma unroll
    for (int dt = 0; dt < 4; dt++) {
      bf16x8 vb0 = SWZ(Vs, 0, dt * 16 + low, quad);
      bf16x8 vb1 = SWZ(Vs, 1, dt * 16 + low, quad);
      oacc[dt] = __builtin_amdgcn_mfma_f32_16x16x32_bf16(pa0, vb0, oacc[dt], 0, 0, 0);
      oacc[dt] = __builtin_amdgcn_mfma_f32_16x16x32_bf16(pa1, vb1, oacc[dt], 0, 0, 0);
    }
  }

  const int b = bh >> 4, h = bh & 15;
  #pragma unroll
  for (int i = 0; i < 4; i++) {
    const float inv = 1.0f / lrow[i];
    const int row = q0 + w * 16 + quad * 4 + i;
    const size_t base = ((size_t)(b * S_ + row)) * E_ + h * 64 + low;
    #pragma unroll
    for (int dt = 0; dt < 4; dt++)
      ctx[base + dt * 16] = __float2bfloat16(oacc[dt][i] * inv);
  }
}

// ---------------------------------------------------------------------------
// bf16 MFMA GEMM, global_load_lds(16B) staging. PARTIAL: split-K over
// blockIdx.z, each z writes its own fp32 partial buffer (no atomics, no
// bias; bias+sum folded downstream into add_ln).
// ---------------------------------------------------------------------------
template <int RELU, int OUT_BF16, int PARTIAL>
__global__ __launch_bounds__(256) void gemm_mfma(
    const __hip_bfloat16* __restrict__ A, const __hip_bfloat16* __restrict__ Wt,
    const float* __restrict__ bias, void* __restrict__ C0, void* __restrict__ C1,
    int M, int N, int Kblk, int lda) {
  __shared__ __bf16 As[128][32];
  __shared__ __bf16 Bs[128][32];
  const int t = threadIdx.x;
  const int lane = t & 63;
  const int w = t >> 6;
  const int wr = w >> 1, wc = w & 1;
  const int m0 = blockIdx.y * 128, n0 = blockIdx.x * 128;
  void* Cout = (blockIdx.z == 0) ? C0 : C1;

  A += (size_t)blockIdx.z * Kblk;
  Wt += (size_t)blockIdx.z * Kblk;

  floatx4 acc[4][4] = {};
  const int srow = t >> 2;
  const int schunk = (t & 3) * 8;

  const __hip_bfloat16* gA0 = A + (size_t)(m0 + srow) * lda + schunk;
  const __hip_bfloat16* gA1 = A + (size_t)(m0 + srow + 64) * lda + schunk;
  const __hip_bfloat16* gB0 = Wt + (size_t)(n0 + srow) * lda + schunk;
  const __hip_bfloat16* gB1 = Wt + (size_t)(n0 + srow + 64) * lda + schunk;
  ls_char* lA = (ls_char*)&As[0][0] + w * 1024;
  ls_char* lB = (ls_char*)&Bs[0][0] + w * 1024;

  for (int k0 = 0; k0 < Kblk; k0 += 32) {
    __syncthreads();                 // all waves done reading previous tile
    gload_lds16(gA0 + k0, lA);
    gload_lds16(gA1 + k0, lA + 4096);
    gload_lds16(gB0 + k0, lB);
    gload_lds16(gB1 + k0, lB + 4096);
    __syncthreads();                 // vmcnt(0) drain -> tile resident

    bf16x8 af[4], bf[4];
    #pragma unroll
    for (int i = 0; i < 4; i++) {
      af[i] = *(const bf16x8*)&As[wr * 64 + i * 16 + (lane & 15)][(lane >> 4) * 8];
      bf[i] = *(const bf16x8*)&Bs[wc * 64 + i * 16 + (lane & 15)][(lane >> 4) * 8];
    }
    #pragma unroll
    for (int mi = 0; mi < 4; mi++)
      #pragma unroll
      for (int ni = 0; ni < 4; ni++)
        acc[mi][ni] = __builtin_amdgcn_mfma_f32_16x16x32_bf16(
            af[mi], bf[ni], acc[mi][ni], 0, 0, 0);
  }

  const int cil = lane & 15;
  const int quad = lane >> 4;
  #pragma unroll
  for (int ni = 0; ni < 4; ni++) {
    const int col = n0 + wc * 64 + ni * 16 + cil;
    const float bb = PARTIAL ? 0.f : bias[col];
    #pragma unroll
    for (int mi = 0; mi < 4; mi++) {
      const int row = m0 + wr * 64 + mi * 16 + quad * 4;
      #pragma unroll
      for (int i = 0; i < 4; i++) {
        if (PARTIAL) {
          ((float*)Cout)[(size_t)(row + i) * N + col] = acc[mi][ni][i];
        } else {
          float vv = acc[mi][ni][i] + bb;
          if (RELU) vv = fmaxf(vv, 0.f);
          if (OUT_BF16)
            ((__hip_bfloat16*)Cout)[(size_t)(row + i) * N + col] = __float2bfloat16(vv);
          else
            ((float*)Cout)[(size_t)(row + i) * N + col] = vv;
        }
      }
    }
  }
}

// ---------------------------------------------------------------------------
// out = LayerNorm(a0 [+ a1] + bias + r)*g + b ; optional secondary bf16 out.
// a1 = second split-K partial; bias added BEFORE LN stats (matches reference
// residual ordering).
// ---------------------------------------------------------------------------
template <int EMIT_BF16>
__global__ __launch_bounds__(256) void add_ln(
    const float* __restrict__ a0, const float* __restrict__ a1,
    const float* __restrict__ r, const float* __restrict__ bias,
    const float* __restrict__ g, const float* __restrict__ bt,
    float* __restrict__ out, __hip_bfloat16* __restrict__ outb) {
  __shared__ float red[16];
  const int tok = blockIdx.x, t = threadIdx.x;
  float4 av = ((const float4*)(a0 + (size_t)tok * E_))[t];
  float4 a2 = ((const float4*)(a1 + (size_t)tok * E_))[t];
  float4 rv = ((const float4*)(r + (size_t)tok * E_))[t];
  float4 cv = ((const float4*)bias)[t];
  float4 x;
  x.x = av.x + a2.x + rv.x + cv.x; x.y = av.y + a2.y + rv.y + cv.y;
  x.z = av.z + a2.z + rv.z + cv.z; x.w = av.w + a2.w + rv.w + cv.w;
  float sum = x.x + x.y + x.z + x.w;
  float ssq = x.x * x.x + x.y * x.y + x.z * x.z + x.w * x.w;
  #pragma unroll
  for (int off = 32; off >= 1; off >>= 1) {
    sum += __shfl_down(sum, off, 64);
    ssq += __shfl_down(ssq, off, 64);
  }
  const int wave = t >> 6;
  if ((t & 63) == 0) { red[wave] = sum; red[4 + wave] = ssq; }
  __syncthreads();
  if (t == 0) {
    float s = red[0] + red[1] + red[2] + red[3];
    float qq = red[4] + red[5] + red[6] + red[7];
    float mu = s * (1.0f / E_);
    red[8] = mu;
    red[9] = qq * (1.0f / E_) - mu * mu;
  }
  __syncthreads();
  const float mu = red[8];
  const float inv = rsqrtf(red[9] + 1e-5f);
  float4 gv = ((const float4*)g)[t];
  float4 bv = ((const float4*)bt)[t];
  float4 o;
  o.x = (x.x - mu) * inv * gv.x + bv.x;
  o.y = (x.y - mu) * inv * gv.y + bv.y;
  o.z = (x.z - mu) * inv * gv.z + bv.z;
  o.w = (x.w - mu) * inv * gv.w + bv.w;
  ((float4*)(out + (size_t)tok * E_))[t] = o;
  if (EMIT_BF16) {
    b4s ob;
    ob.x = __float2bfloat16(o.x); ob.y = __float2bfloat16(o.y);
    ob.z = __float2bfloat16(o.z); ob.w = __float2bfloat16(o.w);
    *(b4s*)(outb + (size_t)tok * E_ + t * 4) = ob;
  }
}

// ---------------------------------------------------------------------------
extern "C" void kernel_launch(void* const* d_in, const int* in_sizes, int n_in,
                              void* d_out, int out_size, void* d_ws, size_t ws_size,
                              hipStream_t stream) {
  const float* queries = (const float*)d_in[0];
  const float* keys    = (const float*)d_in[1];
  const float* values  = (const float*)d_in[2];
  const float* Wq  = (const float*)d_in[4];
  const float* Wk  = (const float*)d_in[5];
  const float* Wv  = (const float*)d_in[6];
  const float* Wfc = (const float*)d_in[7];
  const float* bfc = (const float*)d_in[8];
  const float* W1  = (const float*)d_in[9];
  const float* b1  = (const float*)d_in[10];
  const float* W2  = (const float*)d_in[11];
  const float* b2  = (const float*)d_in[12];
  const float* ln1_g = (const float*)d_in[13];
  const float* ln1_b = (const float*)d_in[14];
  const float* ln2_g = (const float*)d_in[15];
  const float* ln2_b = (const float*)d_in[16];

  const size_t M1 = 1048576;
  float* ws = (float*)d_ws;
  float* P0  = ws;             // 4M fl: split-K partial 0 (ATT then X)
  float* P1  = ws + 4 * M1;    // 4M fl: split-K partial 1
  float* Hf  = ws + 8 * M1;    // 4M fl
  __hip_bfloat16* bb = (__hip_bfloat16*)(ws + 12 * M1);
  __hip_bfloat16* CTXb = bb;                  //  4M
  __hip_bfloat16* Hb   = bb + 4 * M1;         //  4M
  __hip_bfloat16* Wfcb = bb + 8 * M1;         //  1M
  __hip_bfloat16* W1b  = bb + 9 * M1;         //  4M
  __hip_bfloat16* W2b  = bb + 13 * M1;        //  4M
  // attention temps (17M..37M) alias FF1b (17M..33M): FF1b written after attn
  __hip_bfloat16* Qhi  = bb + 17 * M1;        //  4M
  __hip_bfloat16* Qlo  = bb + 21 * M1;        //  4M
  __hip_bfloat16* Khi  = bb + 25 * M1;        //  4M
  __hip_bfloat16* Klo  = bb + 29 * M1;        //  4M
  __hip_bfloat16* Vtb  = bb + 33 * M1;        //  4M
  __hip_bfloat16* FF1b = bb + 17 * M1;        // 16M (after attention)
  __hip_bfloat16* Whlb = bb + 37 * M1;        // 24K
  float* out = (float*)d_out;

  cast_f2b<<<(E_ * E_ / 4 + 255) / 256, 256, 0, stream>>>(Wfc, Wfcb, E_ * E_ / 4);
  cast_f2b<<<(4 * E_ * E_ / 4 + 255) / 256, 256, 0, stream>>>(W1, W1b, 4 * E_ * E_ / 4);
  cast_f2b<<<(4 * E_ * E_ / 4 + 255) / 256, 256, 0, stream>>>(W2, W2b, 4 * E_ * E_ / 4);
  cast_whl<<<12, 256, 0, stream>>>(Wq, Wk, Wv, Whlb);

  qkv_fused<<<dim3(S_ / 64, B_ * H_), 256, 0, stream>>>(
      queries, keys, values, Whlb, Qhi, Qlo, Khi, Klo, Vtb);
  attn_mfma<<<dim3(S_ / 64, B_ * H_), 256, 0, stream>>>(Qhi, Qlo, Khi, Klo, Vtb, CTXb);
  // fc: split-K=2 (K=1024 -> 512/block) -> partials P0,P1; bias in add_ln
  gemm_mfma<0, 0, 1><<<dim3(E_ / 128, TOK / 128, 2), 256, 0, stream>>>(
      CTXb, Wfcb, nullptr, P0, P1, TOK, E_, 512, E_);
  add_ln<1><<<TOK, 256, 0, stream>>>(P0, P1, queries, bfc, ln1_g, ln1_b, Hf, Hb);
  // FFN1: full-K, bias+ReLU, bf16 out (grid 1024)
  gemm_mfma<1, 1, 0><<<dim3(4 * E_ / 128, TOK / 128, 1), 256, 0, stream>>>(
      Hb, W1b, b1, FF1b, FF1b, TOK, 4 * E_, E_, E_);
  // FFN2: split-K=2 (K=4096 -> 2048/block) -> partials P0,P1 (ATT dead)
  gemm_mfma<0, 0, 1><<<dim3(E_ / 128, TOK / 128, 2), 256, 0, stream>>>(
      FF1b, W2b, nullptr, P0, P1, TOK, E_, 2048, 4 * E_);
  add_ln<0><<<TOK, 256, 0, stream>>>(P0, P1, Hf, b2, ln2_g, ln2_b, out, nullptr);
}

// Round 7
// 475.145 us; speedup vs baseline: 1.1372x; 1.0582x over previous
//
#include <hip/hip_runtime.h>
#include <hip/hip_bf16.h>
#include <math.h>

#define B_ 2
#define S_ 2048
#define E_ 1024
#define H_ 16
#define D_ 64
#define TOK (B_*S_)          // 4096 tokens
#define SCALE 45.254833995939045f   // sqrt(2048): reference's softmax(scores / S**-0.5)

typedef __bf16 bf16x8 __attribute__((ext_vector_type(8)));
typedef float floatx4 __attribute__((ext_vector_type(4)));
struct b4s { __hip_bfloat16 x, y, z, w; };   // 8-byte packed bf16 quad

typedef const __attribute__((address_space(1))) char ga_char;
typedef __attribute__((address_space(3))) char ls_char;

// async 16B/lane global->LDS copy; lds dest = wave-uniform base + lane*16
__device__ __forceinline__ void gload_lds16(const void* g, ls_char* l) {
  __builtin_amdgcn_global_load_lds((ga_char*)g, l, 16, 0, 0);
}

// XOR chunk swizzle for [2][64][32]-bf16 tiles (validated round 6)
#define SWZ(arr, half, row, qpos) \
  (*(bf16x8*)&arr[half][row][(((qpos) ^ ((row) & 3)) * 8)])

// ---------------------------------------------------------------------------
// fp32 -> bf16 cast (for big weights)
// ---------------------------------------------------------------------------
__global__ __launch_bounds__(256) void cast_f2b(
    const float* __restrict__ in, __hip_bfloat16* __restrict__ out, int n4) {
  int i = blockIdx.x * 256 + threadIdx.x;
  if (i < n4) {
    float4 v = ((const float4*)in)[i];
    b4s o;
    o.x = __float2bfloat16(v.x); o.y = __float2bfloat16(v.y);
    o.z = __float2bfloat16(v.z); o.w = __float2bfloat16(v.w);
    *(b4s*)(out + (size_t)i * 4) = o;
  }
}

// ---------------------------------------------------------------------------
// Wq/Wk/Wv (64x64 fp32) -> hi/lo bf16 split, layout [m][2][4096]
// ---------------------------------------------------------------------------
__global__ __launch_bounds__(256) void cast_whl(
    const float* __restrict__ Wq, const float* __restrict__ Wk,
    const float* __restrict__ Wv, __hip_bfloat16* __restrict__ Whl) {
  const int idx = blockIdx.x * 256 + threadIdx.x;   // 0..3071
  const int m = idx >> 10;
  const int off = (idx & 1023) * 4;
  const float* W = (m == 0) ? Wq : (m == 1) ? Wk : Wv;
  float4 v = *(const float4*)(W + off);
  b4s hi, lo;
  hi.x = __float2bfloat16(v.x); lo.x = __float2bfloat16(v.x - __bfloat162float(hi.x));
  hi.y = __float2bfloat16(v.y); lo.y = __float2bfloat16(v.y - __bfloat162float(hi.y));
  hi.z = __float2bfloat16(v.z); lo.z = __float2bfloat16(v.z - __bfloat162float(hi.z));
  hi.w = __float2bfloat16(v.w); lo.w = __float2bfloat16(v.w - __bfloat162float(hi.w));
  *(b4s*)(Whl + (size_t)m * 8192 + off) = hi;
  *(b4s*)(Whl + (size_t)m * 8192 + 4096 + off) = lo;
}

// ---------------------------------------------------------------------------
// Fused QKV projection + hi/lo split + V transpose (unchanged from round 6)
// ---------------------------------------------------------------------------
__global__ __launch_bounds__(256) void qkv_fused(
    const float* __restrict__ xq, const float* __restrict__ xk,
    const float* __restrict__ xv, const __hip_bfloat16* __restrict__ Whl,
    __hip_bfloat16* __restrict__ qhi, __hip_bfloat16* __restrict__ qlo,
    __hip_bfloat16* __restrict__ khi, __hip_bfloat16* __restrict__ klo,
    __hip_bfloat16* __restrict__ vt) {
  __shared__ __bf16 Xh[2][64][32], Xl[2][64][32];
  __shared__ __bf16 Vt[64][72];
  const int t = threadIdx.x, lane = t & 63, w = t >> 6;
  const int quad = lane >> 4, low = lane & 15;
  const int bh = blockIdx.y;
  const int b = bh >> 4, h = bh & 15;
  const int s0 = blockIdx.x * 64;
  const int sr = t >> 2;
  const int sc = (t & 3) * 16;
  const int scc = sc >> 5;
  const int p0 = (sc & 31) >> 3;   // logical 16B chunk within half: 0 or 2

  for (int m = 0; m < 3; m++) {
    const float* xin = (m == 0) ? xq : (m == 1) ? xk : xv;
    const __hip_bfloat16* Wh = Whl + (size_t)m * 8192;

    __syncthreads();
    {
      const float* src = xin + ((size_t)(b * S_ + s0 + sr)) * E_ + h * 64 + sc;
      float4 f0 = *(const float4*)(src);
      float4 f1 = *(const float4*)(src + 4);
      float4 f2 = *(const float4*)(src + 8);
      float4 f3 = *(const float4*)(src + 12);
      float fv[16] = {f0.x, f0.y, f0.z, f0.w, f1.x, f1.y, f1.z, f1.w,
                      f2.x, f2.y, f2.z, f2.w, f3.x, f3.y, f3.z, f3.w};
      bf16x8 hi0, hi1, lo0, lo1;
      #pragma unroll
      for (int j = 0; j < 8; j++) {
        hi0[j] = (__bf16)fv[j];
        lo0[j] = (__bf16)(fv[j] - (float)hi0[j]);
        hi1[j] = (__bf16)fv[8 + j];
        lo1[j] = (__bf16)(fv[8 + j] - (float)hi1[j]);
      }
      SWZ(Xh, scc, sr, p0) = hi0;
      SWZ(Xh, scc, sr, p0 + 1) = hi1;
      SWZ(Xl, scc, sr, p0) = lo0;
      SWZ(Xl, scc, sr, p0 + 1) = lo1;
    }
    __syncthreads();

    bf16x8 ah[2], al[2];
    #pragma unroll
    for (int c = 0; c < 2; c++) {
      ah[c] = SWZ(Xh, c, w * 16 + low, quad);
      al[c] = SWZ(Xl, c, w * 16 + low, quad);
    }

    floatx4 acc[4];
    #pragma unroll
    for (int nn = 0; nn < 4; nn++) {
      floatx4 a = {};
      #pragma unroll
      for (int c = 0; c < 2; c++) {
        const __hip_bfloat16* wp = Wh + (nn * 16 + low) * 64 + c * 32 + quad * 8;
        bf16x8 wh_ = *(const bf16x8*)wp;
        bf16x8 wl_ = *(const bf16x8*)(wp + 4096);
        a = __builtin_amdgcn_mfma_f32_16x16x32_bf16(ah[c], wh_, a, 0, 0, 0);
        a = __builtin_amdgcn_mfma_f32_16x16x32_bf16(al[c], wh_, a, 0, 0, 0);
        a = __builtin_amdgcn_mfma_f32_16x16x32_bf16(ah[c], wl_, a, 0, 0, 0);
      }
      acc[nn] = a;
    }

    if (m < 2) {
      __hip_bfloat16* dh = (m == 0) ? qhi : khi;
      __hip_bfloat16* dl = (m == 0) ? qlo : klo;
      #pragma unroll
      for (int nn = 0; nn < 4; nn++) {
        #pragma unroll
        for (int i = 0; i < 4; i++) {
          const int s = s0 + w * 16 + quad * 4 + i;
          const int d = nn * 16 + low;
          const size_t adr = ((size_t)bh * S_ + s) * 64 + d;
          const float f = acc[nn][i];
          const __hip_bfloat16 hb = __float2bfloat16(f);
          dh[adr] = hb;
          dl[adr] = __float2bfloat16(f - __bfloat162float(hb));
        }
      }
    } else {
      #pragma unroll
      for (int nn = 0; nn < 4; nn++)
        #pragma unroll
        for (int i = 0; i < 4; i++)
          Vt[nn * 16 + low][w * 16 + quad * 4 + i] = (__bf16)acc[nn][i];
      __syncthreads();
      const int dr = t >> 2;
      const int scl = (t & 3) * 16;
      __hip_bfloat16* dst = vt + ((size_t)bh * 64 + dr) * S_ + s0 + scl;
      bf16x8 o0 = *(const bf16x8*)&Vt[dr][scl];
      bf16x8 o1 = *(const bf16x8*)&Vt[dr][scl + 8];
      *(bf16x8*)dst = o0;
      *(bf16x8*)(dst + 8) = o1;
    }
  }
}

// ---------------------------------------------------------------------------
// MFMA flash attention, round-7 restructure:
//  - 512-thread blocks (8 waves), 128 q-rows per block, grid (S/128, B*H).
//  - Q fragments loaded DIRECTLY from global (A-operand layout row=low,
//    k=quad*8+j is contiguous in the [bh][s][d] buffers) -> no Q LDS.
//  - K/V staging shared by 8 waves: 1 b128 load+swizzled write per tile per
//    thread per iter. LDS = 24 KB tiles + 20 KB Ps = 44.5 KB -> 2 blocks/CU
//    = 16 waves/CU (~50% occupancy vs 27%).
// ---------------------------------------------------------------------------
__global__ __launch_bounds__(512) void attn_mfma(
    const __hip_bfloat16* __restrict__ Qhi, const __hip_bfloat16* __restrict__ Qlo,
    const __hip_bfloat16* __restrict__ Khi, const __hip_bfloat16* __restrict__ Klo,
    const __hip_bfloat16* __restrict__ Vtg, __hip_bfloat16* __restrict__ ctx) {
  __shared__ __bf16 Kh[2][64][32], Kl[2][64][32];
  __shared__ __bf16 Vs[2][64][32];
  __shared__ __bf16 Ps[8][2][16][40];
  const int t = threadIdx.x, lane = t & 63, w = t >> 6;   // w: 0..7
  const int quad = lane >> 4, low = lane & 15;
  const int bh = blockIdx.y;
  const int q0 = blockIdx.x * 128;
  const int qw = q0 + w * 16;       // this wave's q-row base

  // staging map: 512 threads x 1 chunk per tile: row t>>3, chunk t&7
  const int sr = t >> 3;            // 0..63
  const int sc = (t & 7) * 8;       // bf16 col 0..56 step 8
  const int scc = sc >> 5;          // half 0/1
  const int spos = (sc & 31) >> 3;  // chunk-in-half 0..3

  // Q fragments straight from global
  bf16x8 qh[2], ql[2];
  {
    const size_t qbase = ((size_t)bh * S_ + qw + low) * 64 + quad * 8;
    qh[0] = *(const bf16x8*)(Qhi + qbase);
    qh[1] = *(const bf16x8*)(Qhi + qbase + 32);
    ql[0] = *(const bf16x8*)(Qlo + qbase);
    ql[1] = *(const bf16x8*)(Qlo + qbase + 32);
  }

  floatx4 oacc[4] = {};
  float mrow[4], lrow[4];
  #pragma unroll
  for (int i = 0; i < 4; i++) { mrow[i] = -1e30f; lrow[i] = 0.f; }

  for (int kt = 0; kt < S_ / 64; kt++) {
    const size_t gk = ((size_t)bh * S_ + kt * 64 + sr) * 64 + sc;
    const size_t gv = ((size_t)bh * 64 + sr) * S_ + kt * 64 + sc;
    bf16x8 khv = *(const bf16x8*)(Khi + gk);
    bf16x8 klv = *(const bf16x8*)(Klo + gk);
    bf16x8 vvv = *(const bf16x8*)(Vtg + gv);
    __syncthreads();                     // prior tile fully consumed
    SWZ(Kh, scc, sr, spos) = khv;
    SWZ(Kl, scc, sr, spos) = klv;
    SWZ(Vs, scc, sr, spos) = vvv;
    __syncthreads();

    floatx4 sa[4];
    #pragma unroll
    for (int nn = 0; nn < 4; nn++) {
      bf16x8 kh[2], kl[2];
      #pragma unroll
      for (int c = 0; c < 2; c++) {
        kh[c] = SWZ(Kh, c, nn * 16 + low, quad);
        kl[c] = SWZ(Kl, c, nn * 16 + low, quad);
      }
      floatx4 s = {};
      s = __builtin_amdgcn_mfma_f32_16x16x32_bf16(qh[0], kh[0], s, 0, 0, 0);
      s = __builtin_amdgcn_mfma_f32_16x16x32_bf16(qh[1], kh[1], s, 0, 0, 0);
      s = __builtin_amdgcn_mfma_f32_16x16x32_bf16(ql[0], kh[0], s, 0, 0, 0);
      s = __builtin_amdgcn_mfma_f32_16x16x32_bf16(ql[1], kh[1], s, 0, 0, 0);
      s = __builtin_amdgcn_mfma_f32_16x16x32_bf16(qh[0], kl[0], s, 0, 0, 0);
      s = __builtin_amdgcn_mfma_f32_16x16x32_bf16(qh[1], kl[1], s, 0, 0, 0);
      sa[nn] = s;
    }

    float pv[4][4];
    #pragma unroll
    for (int i = 0; i < 4; i++) {
      float s0 = sa[0][i] * SCALE, s1 = sa[1][i] * SCALE;
      float s2 = sa[2][i] * SCALE, s3 = sa[3][i] * SCALE;
      float rmax = fmaxf(fmaxf(s0, s1), fmaxf(s2, s3));
      rmax = fmaxf(rmax, __shfl_xor(rmax, 1, 64));
      rmax = fmaxf(rmax, __shfl_xor(rmax, 2, 64));
      rmax = fmaxf(rmax, __shfl_xor(rmax, 4, 64));
      rmax = fmaxf(rmax, __shfl_xor(rmax, 8, 64));
      const float nm = fmaxf(mrow[i], rmax);
      const float al = __expf(mrow[i] - nm);
      mrow[i] = nm;
      const float p0_ = __expf(s0 - nm), p1_ = __expf(s1 - nm);
      const float p2_ = __expf(s2 - nm), p3_ = __expf(s3 - nm);
      pv[0][i] = p0_; pv[1][i] = p1_; pv[2][i] = p2_; pv[3][i] = p3_;
      float rs = (p0_ + p1_) + (p2_ + p3_);
      rs += __shfl_xor(rs, 1, 64);
      rs += __shfl_xor(rs, 2, 64);
      rs += __shfl_xor(rs, 4, 64);
      rs += __shfl_xor(rs, 8, 64);
      lrow[i] = lrow[i] * al + rs;
      oacc[0][i] *= al; oacc[1][i] *= al; oacc[2][i] *= al; oacc[3][i] *= al;
    }

    #pragma unroll
    for (int nn = 0; nn < 4; nn++)
      #pragma unroll
      for (int i = 0; i < 4; i++)
        Ps[w][nn >> 1][quad * 4 + i][(nn & 1) * 16 + low] = (__bf16)pv[nn][i];
    bf16x8 pa0 = *(const bf16x8*)&Ps[w][0][low][quad * 8];
    bf16x8 pa1 = *(const bf16x8*)&Ps[w][1][low][quad * 8];

    #pragma unroll
    for (int dt = 0; dt < 4; dt++) {
      bf16x8 vb0 = SWZ(Vs, 0, dt * 16 + low, quad);
      bf16x8 vb1 = SWZ(Vs, 1, dt * 16 + low, quad);
      oacc[dt] = __builtin_amdgcn_mfma_f32_16x16x32_bf16(pa0, vb0, oacc[dt], 0, 0, 0);
      oacc[dt] = __builtin_amdgcn_mfma_f32_16x16x32_bf16(pa1, vb1, oacc[dt], 0, 0, 0);
    }
  }

  const int b = bh >> 4, h = bh & 15;
  #pragma unroll
  for (int i = 0; i < 4; i++) {
    const float inv = 1.0f / lrow[i];
    const int row = qw + quad * 4 + i;
    const size_t base = ((size_t)(b * S_ + row)) * E_ + h * 64 + low;
    #pragma unroll
    for (int dt = 0; dt < 4; dt++)
      ctx[base + dt * 16] = __float2bfloat16(oacc[dt][i] * inv);
  }
}

// ---------------------------------------------------------------------------
// bf16 MFMA GEMM, global_load_lds(16B) staging. PARTIAL: split-K over
// blockIdx.z, each z writes its own fp32 partial buffer.
// ---------------------------------------------------------------------------
template <int RELU, int OUT_BF16, int PARTIAL>
__global__ __launch_bounds__(256) void gemm_mfma(
    const __hip_bfloat16* __restrict__ A, const __hip_bfloat16* __restrict__ Wt,
    const float* __restrict__ bias, void* __restrict__ C0, void* __restrict__ C1,
    int M, int N, int Kblk, int lda) {
  __shared__ __bf16 As[128][32];
  __shared__ __bf16 Bs[128][32];
  const int t = threadIdx.x;
  const int lane = t & 63;
  const int w = t >> 6;
  const int wr = w >> 1, wc = w & 1;
  const int m0 = blockIdx.y * 128, n0 = blockIdx.x * 128;
  void* Cout = (blockIdx.z == 0) ? C0 : C1;

  A += (size_t)blockIdx.z * Kblk;
  Wt += (size_t)blockIdx.z * Kblk;

  floatx4 acc[4][4] = {};
  const int srow = t >> 2;
  const int schunk = (t & 3) * 8;

  const __hip_bfloat16* gA0 = A + (size_t)(m0 + srow) * lda + schunk;
  const __hip_bfloat16* gA1 = A + (size_t)(m0 + srow + 64) * lda + schunk;
  const __hip_bfloat16* gB0 = Wt + (size_t)(n0 + srow) * lda + schunk;
  const __hip_bfloat16* gB1 = Wt + (size_t)(n0 + srow + 64) * lda + schunk;
  ls_char* lA = (ls_char*)&As[0][0] + w * 1024;
  ls_char* lB = (ls_char*)&Bs[0][0] + w * 1024;

  for (int k0 = 0; k0 < Kblk; k0 += 32) {
    __syncthreads();
    gload_lds16(gA0 + k0, lA);
    gload_lds16(gA1 + k0, lA + 4096);
    gload_lds16(gB0 + k0, lB);
    gload_lds16(gB1 + k0, lB + 4096);
    __syncthreads();

    bf16x8 af[4], bf[4];
    #pragma unroll
    for (int i = 0; i < 4; i++) {
      af[i] = *(const bf16x8*)&As[wr * 64 + i * 16 + (lane & 15)][(lane >> 4) * 8];
      bf[i] = *(const bf16x8*)&Bs[wc * 64 + i * 16 + (lane & 15)][(lane >> 4) * 8];
    }
    #pragma unroll
    for (int mi = 0; mi < 4; mi++)
      #pragma unroll
      for (int ni = 0; ni < 4; ni++)
        acc[mi][ni] = __builtin_amdgcn_mfma_f32_16x16x32_bf16(
            af[mi], bf[ni], acc[mi][ni], 0, 0, 0);
  }

  const int cil = lane & 15;
  const int quad = lane >> 4;
  #pragma unroll
  for (int ni = 0; ni < 4; ni++) {
    const int col = n0 + wc * 64 + ni * 16 + cil;
    const float bb = PARTIAL ? 0.f : bias[col];
    #pragma unroll
    for (int mi = 0; mi < 4; mi++) {
      const int row = m0 + wr * 64 + mi * 16 + quad * 4;
      #pragma unroll
      for (int i = 0; i < 4; i++) {
        if (PARTIAL) {
          ((float*)Cout)[(size_t)(row + i) * N + col] = acc[mi][ni][i];
        } else {
          float vv = acc[mi][ni][i] + bb;
          if (RELU) vv = fmaxf(vv, 0.f);
          if (OUT_BF16)
            ((__hip_bfloat16*)Cout)[(size_t)(row + i) * N + col] = __float2bfloat16(vv);
          else
            ((float*)Cout)[(size_t)(row + i) * N + col] = vv;
        }
      }
    }
  }
}

// ---------------------------------------------------------------------------
// out = LayerNorm(a0 + a1 + bias + r)*g + b ; optional secondary bf16 out.
// ---------------------------------------------------------------------------
template <int EMIT_BF16>
__global__ __launch_bounds__(256) void add_ln(
    const float* __restrict__ a0, const float* __restrict__ a1,
    const float* __restrict__ r, const float* __restrict__ bias,
    const float* __restrict__ g, const float* __restrict__ bt,
    float* __restrict__ out, __hip_bfloat16* __restrict__ outb) {
  __shared__ float red[16];
  const int tok = blockIdx.x, t = threadIdx.x;
  float4 av = ((const float4*)(a0 + (size_t)tok * E_))[t];
  float4 a2 = ((const float4*)(a1 + (size_t)tok * E_))[t];
  float4 rv = ((const float4*)(r + (size_t)tok * E_))[t];
  float4 cv = ((const float4*)bias)[t];
  float4 x;
  x.x = av.x + a2.x + rv.x + cv.x; x.y = av.y + a2.y + rv.y + cv.y;
  x.z = av.z + a2.z + rv.z + cv.z; x.w = av.w + a2.w + rv.w + cv.w;
  float sum = x.x + x.y + x.z + x.w;
  float ssq = x.x * x.x + x.y * x.y + x.z * x.z + x.w * x.w;
  #pragma unroll
  for (int off = 32; off >= 1; off >>= 1) {
    sum += __shfl_down(sum, off, 64);
    ssq += __shfl_down(ssq, off, 64);
  }
  const int wave = t >> 6;
  if ((t & 63) == 0) { red[wave] = sum; red[4 + wave] = ssq; }
  __syncthreads();
  if (t == 0) {
    float s = red[0] + red[1] + red[2] + red[3];
    float qq = red[4] + red[5] + red[6] + red[7];
    float mu = s * (1.0f / E_);
    red[8] = mu;
    red[9] = qq * (1.0f / E_) - mu * mu;
  }
  __syncthreads();
  const float mu = red[8];
  const float inv = rsqrtf(red[9] + 1e-5f);
  float4 gv = ((const float4*)g)[t];
  float4 bv = ((const float4*)bt)[t];
  float4 o;
  o.x = (x.x - mu) * inv * gv.x + bv.x;
  o.y = (x.y - mu) * inv * gv.y + bv.y;
  o.z = (x.z - mu) * inv * gv.z + bv.z;
  o.w = (x.w - mu) * inv * gv.w + bv.w;
  ((float4*)(out + (size_t)tok * E_))[t] = o;
  if (EMIT_BF16) {
    b4s ob;
    ob.x = __float2bfloat16(o.x); ob.y = __float2bfloat16(o.y);
    ob.z = __float2bfloat16(o.z); ob.w = __float2bfloat16(o.w);
    *(b4s*)(outb + (size_t)tok * E_ + t * 4) = ob;
  }
}

// ---------------------------------------------------------------------------
extern "C" void kernel_launch(void* const* d_in, const int* in_sizes, int n_in,
                              void* d_out, int out_size, void* d_ws, size_t ws_size,
                              hipStream_t stream) {
  const float* queries = (const float*)d_in[0];
  const float* keys    = (const float*)d_in[1];
  const float* values  = (const float*)d_in[2];
  const float* Wq  = (const float*)d_in[4];
  const float* Wk  = (const float*)d_in[5];
  const float* Wv  = (const float*)d_in[6];
  const float* Wfc = (const float*)d_in[7];
  const float* bfc = (const float*)d_in[8];
  const float* W1  = (const float*)d_in[9];
  const float* b1  = (const float*)d_in[10];
  const float* W2  = (const float*)d_in[11];
  const float* b2  = (const float*)d_in[12];
  const float* ln1_g = (const float*)d_in[13];
  const float* ln1_b = (const float*)d_in[14];
  const float* ln2_g = (const float*)d_in[15];
  const float* ln2_b = (const float*)d_in[16];

  const size_t M1 = 1048576;
  float* ws = (float*)d_ws;
  float* P0  = ws;             // 4M fl: split-K partial 0
  float* P1  = ws + 4 * M1;    // 4M fl: split-K partial 1
  float* Hf  = ws + 8 * M1;    // 4M fl
  __hip_bfloat16* bb = (__hip_bfloat16*)(ws + 12 * M1);
  __hip_bfloat16* CTXb = bb;                  //  4M
  __hip_bfloat16* Hb   = bb + 4 * M1;         //  4M
  __hip_bfloat16* Wfcb = bb + 8 * M1;         //  1M
  __hip_bfloat16* W1b  = bb + 9 * M1;         //  4M
  __hip_bfloat16* W2b  = bb + 13 * M1;        //  4M
  // attention temps (17M..37M) alias FF1b (17M..33M): FF1b written after attn
  __hip_bfloat16* Qhi  = bb + 17 * M1;        //  4M
  __hip_bfloat16* Qlo  = bb + 21 * M1;        //  4M
  __hip_bfloat16* Khi  = bb + 25 * M1;        //  4M
  __hip_bfloat16* Klo  = bb + 29 * M1;        //  4M
  __hip_bfloat16* Vtb  = bb + 33 * M1;        //  4M
  __hip_bfloat16* FF1b = bb + 17 * M1;        // 16M (after attention)
  __hip_bfloat16* Whlb = bb + 37 * M1;        // 24K
  float* out = (float*)d_out;

  cast_f2b<<<(E_ * E_ / 4 + 255) / 256, 256, 0, stream>>>(Wfc, Wfcb, E_ * E_ / 4);
  cast_f2b<<<(4 * E_ * E_ / 4 + 255) / 256, 256, 0, stream>>>(W1, W1b, 4 * E_ * E_ / 4);
  cast_f2b<<<(4 * E_ * E_ / 4 + 255) / 256, 256, 0, stream>>>(W2, W2b, 4 * E_ * E_ / 4);
  cast_whl<<<12, 256, 0, stream>>>(Wq, Wk, Wv, Whlb);

  qkv_fused<<<dim3(S_ / 64, B_ * H_), 256, 0, stream>>>(
      queries, keys, values, Whlb, Qhi, Qlo, Khi, Klo, Vtb);
  attn_mfma<<<dim3(S_ / 128, B_ * H_), 512, 0, stream>>>(
      Qhi, Qlo, Khi, Klo, Vtb, CTXb);
  gemm_mfma<0, 0, 1><<<dim3(E_ / 128, TOK / 128, 2), 256, 0, stream>>>(
      CTXb, Wfcb, nullptr, P0, P1, TOK, E_, 512, E_);
  add_ln<1><<<TOK, 256, 0, stream>>>(P0, P1, queries, bfc, ln1_g, ln1_b, Hf, Hb);
  gemm_mfma<1, 1, 0><<<dim3(4 * E_ / 128, TOK / 128, 1), 256, 0, stream>>>(
      Hb, W1b, b1, FF1b, FF1b, TOK, 4 * E_, E_, E_);
  gemm_mfma<0, 0, 1><<<dim3(E_ / 128, TOK / 128, 2), 256, 0, stream>>>(
      FF1b, W2b, nullptr, P0, P1, TOK, E_, 2048, 4 * E_);
  add_ln<0><<<TOK, 256, 0, stream>>>(P0, P1, Hf, b2, ln2_g, ln2_b, out, nullptr);
}